// Round 9
// baseline (583.843 us; speedup 1.0000x reference)
//
#include <hip/hip_runtime.h>
#include <hip/hip_bf16.h>
#include <cstdint>
#include <cstddef>

#define N_NODES 20000
#define F_IN    2000
#define H_DIM   128
#define L_DIM   15
#define K_PAD   2048      // padded K for xb/w1r layouts
#define YS      384       // Y fp32 stride (hops 0..2); hop3 lives in bf16 Yb3
#define BM      128
#define BN      64        // 128x64 tiles: 12KB staged/iter, 1280 blocks
#define BK      32
#define I_TILES 157       // ceil(20000/128)

// bank-conflict swizzle: k-slot s of each 32-k group stored at s ^ FSW(row&15).
// Fragment read (quad ^ FSW(l15)) then lands 16 lanes on each of the 8
// bank-quads exactly twice (2-way = free, m136), vs 8-way unswizzled.
#define FSW(r) (((r) + ((r) >> 2)) & 3)

typedef __attribute__((ext_vector_type(4))) float f32x4;
typedef __attribute__((ext_vector_type(8))) short s16x8;
typedef __attribute__((ext_vector_type(8))) unsigned short u16x8;

__device__ __forceinline__ unsigned short f2bf(float f) {
  unsigned int u = __float_as_uint(f);
  u += 0x7fff + ((u >> 16) & 1);   // RNE
  return (unsigned short)(u >> 16);
}

__device__ __forceinline__ unsigned int pkbf(float a, float b) {
  union { __hip_bfloat162 h; unsigned int u; } cv;
  cv.h = __float22bfloat162_rn(make_float2(a, b));
  return cv.u;
}

__device__ __forceinline__ float2 bf2f(unsigned int u) {
  float2 r;
  r.x = __uint_as_float(u << 16);
  r.y = __uint_as_float(u & 0xffff0000u);
  return r;
}

// ---- x (fp32 [20000][2000]) -> bf16 [20000][2048], slot-swizzled per 32-k group ----
__global__ __launch_bounds__(256) void k_cvt_x(const float* __restrict__ x,
                                               unsigned short* __restrict__ xb) {
  unsigned int t = blockIdx.x * 256u + threadIdx.x;
  unsigned int row = t >> 8;
  unsigned int colB = (t & 255u) * 8u;
  u16x8 o = {0, 0, 0, 0, 0, 0, 0, 0};
  if (colB < F_IN) {
    const float4 a = *(const float4*)(x + (size_t)row * F_IN + colB);
    const float4 b = *(const float4*)(x + (size_t)row * F_IN + colB + 4);
    o[0] = f2bf(a.x); o[1] = f2bf(a.y); o[2] = f2bf(a.z); o[3] = f2bf(a.w);
    o[4] = f2bf(b.x); o[5] = f2bf(b.y); o[6] = f2bf(b.z); o[7] = f2bf(b.w);
  }
  unsigned int s  = (colB >> 3) & 3;
  unsigned int sp = s ^ FSW(row & 15);
  *(u16x8*)(xb + (size_t)row * K_PAD + (colB & ~31u) + sp * 8) = o;
}

// ---- W1 [8000][128] -> bf16 B^T [512][2048], slot-swizzled per 32-k group ----
__global__ __launch_bounds__(256) void k_cvt_w1(const float* __restrict__ W1,
                                                unsigned short* __restrict__ bt) {
  __shared__ unsigned short tile[128 * 67];
  const int hop = blockIdx.x >> 5;
  const int k0  = (blockIdx.x & 31) * 64;
  const int t = threadIdx.x;
#pragma unroll
  for (int it = 0; it < 8; ++it) {
    int f4 = it * 256 + t;
    int r  = f4 >> 5;
    int c4 = f4 & 31;
    int k = k0 + r;
    float4 v = make_float4(0.f, 0.f, 0.f, 0.f);
    if (k < F_IN) v = *(const float4*)(W1 + (size_t)(hop * F_IN + k) * H_DIM + c4 * 4);
    tile[(c4 * 4 + 0) * 67 + r] = f2bf(v.x);
    tile[(c4 * 4 + 1) * 67 + r] = f2bf(v.y);
    tile[(c4 * 4 + 2) * 67 + r] = f2bf(v.z);
    tile[(c4 * 4 + 3) * 67 + r] = f2bf(v.w);
  }
  __syncthreads();
  const int c = t >> 1, kh = (t & 1) * 32;     // kh: one full 32-k group
  const int fN = FSW(c & 15);
  unsigned short* dst = bt + (size_t)(hop * 128 + c) * K_PAD + k0 + kh;
  const unsigned short* srcp = tile + c * 67 + kh;
#pragma unroll
  for (int q = 0; q < 4; ++q) {
    u16x8 o;
#pragma unroll
    for (int e = 0; e < 8; ++e) o[e] = srcp[q * 8 + e];
    *(u16x8*)(dst + (q ^ fN) * 8) = o;
  }
}

// ---- bf16 MFMA GEMM, 128x64 tiles, swizzled fragment reads ----
// grid = 1280 1D; xcd=b&7, i_tile=(b&7)+8*(b>>6), j_tile=(b>>3)&7
__global__ __launch_bounds__(256) void k_gemm1(const unsigned short* __restrict__ A,
                                               const unsigned short* __restrict__ B,
                                               float* __restrict__ Y,
                                               unsigned short* __restrict__ Yb3) {
  __shared__ unsigned short As[BM * BK];   // 8 KB
  __shared__ unsigned short Bs[BN * BK];   // 4 KB
  const int b = blockIdx.x;
  const int i_tile = (b & 7) + 8 * (b >> 6);
  const int j_tile = (b >> 3) & 7;
  if (i_tile >= I_TILES) return;
  const int rowA0 = i_tile * BM;
  const int colB0 = j_tile * BN;
  const int tid  = threadIdx.x;
  const int lane = tid & 63;
  const int wave = tid >> 6;
  const int wm = (wave >> 1) * 64;
  const int wn = (wave & 1) * 32;
  const int quad = lane >> 4;
  const int l15  = lane & 15;
  const int qs   = (quad ^ FSW(l15)) * 8;   // swizzled slot offset (shorts)
  f32x4 acc[4][2] = {};

  for (int kt = 0; kt < K_PAD; kt += BK) {
#pragma unroll
    for (int r = 0; r < 2; ++r) {
      int c = r * 256 + tid;
      int row = c >> 2;
      int kc = (c & 3) * 8;
      const unsigned short* ga = A + (size_t)(rowA0 + row) * K_PAD + kt + kc;
      __builtin_amdgcn_global_load_lds((const __attribute__((address_space(1))) void*)ga,
                                       (__attribute__((address_space(3))) void*)(As + c * 8),
                                       16, 0, 0);
    }
    {
      int c = tid;
      int row = c >> 2;
      int kc = (c & 3) * 8;
      const unsigned short* gb = B + (size_t)(colB0 + row) * K_PAD + kt + kc;
      __builtin_amdgcn_global_load_lds((const __attribute__((address_space(1))) void*)gb,
                                       (__attribute__((address_space(3))) void*)(Bs + c * 8),
                                       16, 0, 0);
    }
    __syncthreads();
    s16x8 af[4], bfr[2];
#pragma unroll
    for (int i = 0; i < 4; ++i)
      af[i] = *(const s16x8*)(As + (wm + i * 16 + l15) * BK + qs);
#pragma unroll
    for (int j = 0; j < 2; ++j)
      bfr[j] = *(const s16x8*)(Bs + (wn + j * 16 + l15) * BK + qs);
#pragma unroll
    for (int i = 0; i < 4; ++i)
#pragma unroll
      for (int j = 0; j < 2; ++j)
        acc[i][j] = __builtin_amdgcn_mfma_f32_16x16x32_bf16(af[i], bfr[j], acc[i][j], 0, 0, 0);
    __syncthreads();
  }

#pragma unroll
  for (int i = 0; i < 4; ++i) {
    int row0 = rowA0 + wm + i * 16 + quad * 4;
#pragma unroll
    for (int j = 0; j < 2; ++j) {
      int gcol = colB0 + wn + j * 16 + l15;
#pragma unroll
      for (int r = 0; r < 4; ++r) {
        int row = row0 + r;
        if (row < N_NODES) {
          if (j_tile < 6)
            Y[(size_t)row * YS + gcol] = acc[i][j][r];
          else
            Yb3[(size_t)row * H_DIM + (gcol - 384)] = f2bf(acc[i][j][r]);
        }
      }
    }
  }
}

// ---- CSR build (padded to multiple of 16 edges per row) ----
__global__ __launch_bounds__(256) void k_hist(const int* __restrict__ dst,
                                              int* __restrict__ deg, int E) {
  int i = blockIdx.x * 256 + threadIdx.x;
  int e = i * 4;
  if (e + 4 <= E) {
    int4 d4 = *(const int4*)(dst + e);
    atomicAdd(&deg[d4.x], 1); atomicAdd(&deg[d4.y], 1);
    atomicAdd(&deg[d4.z], 1); atomicAdd(&deg[d4.w], 1);
  } else {
    for (; e < E; ++e) atomicAdd(&deg[dst[e]], 1);
  }
}

__global__ __launch_bounds__(1024) void k_scan(const int* __restrict__ deg,
                                               int* __restrict__ rowStart,
                                               int* __restrict__ cursor,
                                               int* __restrict__ realEnd) {
  __shared__ int sums[1024];
  const int t = threadIdx.x;
  const int chunk = (N_NODES + 1023) / 1024;
  int lo = t * chunk;
  int hi = lo + chunk; if (hi > N_NODES) hi = N_NODES;
  int s = 0;
  for (int i = lo; i < hi; ++i) s += (deg[i] + 15) & ~15;
  sums[t] = s;
  __syncthreads();
  for (int off = 1; off < 1024; off <<= 1) {
    int v = sums[t];
    int u = (t >= off) ? sums[t - off] : 0;
    __syncthreads();
    sums[t] = v + u;
    __syncthreads();
  }
  int run = sums[t] - s;
  for (int i = lo; i < hi; ++i) {
    rowStart[i] = run; cursor[i] = run; realEnd[i] = run + deg[i];
    run += (deg[i] + 15) & ~15;
  }
  if (t == 1023) rowStart[N_NODES] = run;
}

__global__ __launch_bounds__(256) void k_scatter(const int* __restrict__ src,
                                                 const int* __restrict__ dst,
                                                 const float* __restrict__ w,
                                                 int* cursor,
                                                 int2* __restrict__ eSW, int E) {
  int e = blockIdx.x * 256 + threadIdx.x;
  if (e >= E) return;
  int p = atomicAdd(&cursor[dst[e]], 1);
  eSW[p] = make_int2(src[e], __float_as_int(w[e]));
}

// fill pad slots [realEnd, nextRowStart) with {src=0, w=0}
__global__ __launch_bounds__(256) void k_pad(const int* __restrict__ rowStart,
                                             const int* __restrict__ realEnd,
                                             int2* __restrict__ eSW) {
  int t = blockIdx.x * 256 + threadIdx.x;
  int d = t >> 4, i = t & 15;
  if (d >= N_NODES) return;
  int s = realEnd[d] + i;
  if (s < rowStart[d + 1]) eSW[s] = make_int2(0, 0);
}

// ---- prop128f: 1 wave/row, padded uniform chunks of 16, 4 edges/instruction ----
__global__ __launch_bounds__(256) void k_prop128f(const int* __restrict__ rowStart,
    const int2* __restrict__ eSW,
    const unsigned short* __restrict__ gsrc,   // bf16 [N_NODES][128]
    const float* __restrict__ addv, int addStride, int addOff,
    unsigned short* __restrict__ outb, float* __restrict__ outf,
    const float* __restrict__ b1, const float* __restrict__ gamma,
    const float* __restrict__ beta, const float* __restrict__ mean,
    const float* __restrict__ var, int doBN) {
  const int lane = threadIdx.x & 63;
  const int wave = threadIdx.x >> 6;
  const int eidx = lane >> 4;        // 0..3
  const int s16  = lane & 15;        // feats [s16*8, s16*8+8)
  const int d = blockIdx.x * 4 + wave;
  const int s0 = rowStart[d], s1 = rowStart[d + 1];
  f32x4 a0 = {0.f, 0.f, 0.f, 0.f};
  f32x4 a1 = {0.f, 0.f, 0.f, 0.f};

  const int nc = (s1 - s0) >> 4;
  int j = s0;
  int2 ed0[4], ed1[4];
  if (nc > 0) {
#pragma unroll
    for (int i = 0; i < 4; ++i) ed0[i] = eSW[j + 4 * i + eidx];
  }
  for (int c = 0; c < nc; ++c) {
    uint4 g[4];
#pragma unroll
    for (int i = 0; i < 4; ++i)
      g[i] = *(const uint4*)(gsrc + (size_t)ed0[i].x * H_DIM + s16 * 8);
    if (c + 1 < nc) {
#pragma unroll
      for (int i = 0; i < 4; ++i) ed1[i] = eSW[j + 16 + 4 * i + eidx];
    }
#pragma unroll
    for (int i = 0; i < 4; ++i) {
      float w = __int_as_float(ed0[i].y);
      float2 p0 = bf2f(g[i].x), p1 = bf2f(g[i].y);
      float2 p2 = bf2f(g[i].z), p3 = bf2f(g[i].w);
      a0.x = fmaf(w, p0.x, a0.x); a0.y = fmaf(w, p0.y, a0.y);
      a0.z = fmaf(w, p1.x, a0.z); a0.w = fmaf(w, p1.y, a0.w);
      a1.x = fmaf(w, p2.x, a1.x); a1.y = fmaf(w, p2.y, a1.y);
      a1.z = fmaf(w, p3.x, a1.z); a1.w = fmaf(w, p3.y, a1.w);
    }
#pragma unroll
    for (int i = 0; i < 4; ++i) ed0[i] = ed1[i];
    j += 16;
  }
  a0.x += __shfl_xor(a0.x, 16); a0.y += __shfl_xor(a0.y, 16);
  a0.z += __shfl_xor(a0.z, 16); a0.w += __shfl_xor(a0.w, 16);
  a1.x += __shfl_xor(a1.x, 16); a1.y += __shfl_xor(a1.y, 16);
  a1.z += __shfl_xor(a1.z, 16); a1.w += __shfl_xor(a1.w, 16);
  a0.x += __shfl_xor(a0.x, 32); a0.y += __shfl_xor(a0.y, 32);
  a0.z += __shfl_xor(a0.z, 32); a0.w += __shfl_xor(a0.w, 32);
  a1.x += __shfl_xor(a1.x, 32); a1.y += __shfl_xor(a1.y, 32);
  a1.z += __shfl_xor(a1.z, 32); a1.w += __shfl_xor(a1.w, 32);
  if (lane >= 16) return;
  const int c8 = s16 * 8;
  const float* ap = addv + (size_t)d * addStride + addOff + c8;
  float4 av0 = *(const float4*)ap;
  float4 av1 = *(const float4*)(ap + 4);
  float r0 = av0.x + a0.x, r1 = av0.y + a0.y, r2 = av0.z + a0.z, r3 = av0.w + a0.w;
  float r4 = av1.x + a1.x, r5 = av1.y + a1.y, r6 = av1.z + a1.z, r7 = av1.w + a1.w;
  if (doBN) {
    float4 bb0 = *(const float4*)(b1 + c8),    bb1 = *(const float4*)(b1 + c8 + 4);
    float4 gg0 = *(const float4*)(gamma + c8), gg1 = *(const float4*)(gamma + c8 + 4);
    float4 be0 = *(const float4*)(beta + c8),  be1 = *(const float4*)(beta + c8 + 4);
    float4 mm0 = *(const float4*)(mean + c8),  mm1 = *(const float4*)(mean + c8 + 4);
    float4 vv0 = *(const float4*)(var + c8),   vv1 = *(const float4*)(var + c8 + 4);
    r0 = (r0 + bb0.x - mm0.x) * rsqrtf(vv0.x + 1e-3f) * gg0.x + be0.x;
    r1 = (r1 + bb0.y - mm0.y) * rsqrtf(vv0.y + 1e-3f) * gg0.y + be0.y;
    r2 = (r2 + bb0.z - mm0.z) * rsqrtf(vv0.z + 1e-3f) * gg0.z + be0.z;
    r3 = (r3 + bb0.w - mm0.w) * rsqrtf(vv0.w + 1e-3f) * gg0.w + be0.w;
    r4 = (r4 + bb1.x - mm1.x) * rsqrtf(vv1.x + 1e-3f) * gg1.x + be1.x;
    r5 = (r5 + bb1.y - mm1.y) * rsqrtf(vv1.y + 1e-3f) * gg1.y + be1.y;
    r6 = (r6 + bb1.z - mm1.z) * rsqrtf(vv1.z + 1e-3f) * gg1.z + be1.z;
    r7 = (r7 + bb1.w - mm1.w) * rsqrtf(vv1.w + 1e-3f) * gg1.w + be1.w;
    r0 = r0 > 0.f ? r0 : 0.f; r1 = r1 > 0.f ? r1 : 0.f;
    r2 = r2 > 0.f ? r2 : 0.f; r3 = r3 > 0.f ? r3 : 0.f;
    r4 = r4 > 0.f ? r4 : 0.f; r5 = r5 > 0.f ? r5 : 0.f;
    r6 = r6 > 0.f ? r6 : 0.f; r7 = r7 > 0.f ? r7 : 0.f;
    float* op = outf + (size_t)d * H_DIM + c8;
    *(float4*)op = make_float4(r0, r1, r2, r3);
    *(float4*)(op + 4) = make_float4(r4, r5, r6, r7);
  } else {
    *(uint4*)(outb + (size_t)d * H_DIM + c8) =
        make_uint4(pkbf(r0, r1), pkbf(r2, r3), pkbf(r4, r5), pkbf(r6, r7));
  }
}

// ---- Y2[20000][64] = H @ W2 (4 hop-blocks of [128][15], stride 16/hop) ----
__global__ __launch_bounds__(256) void k_gemm2(const float* __restrict__ Hh,
                                               const float* __restrict__ W2,
                                               float* __restrict__ Y2) {
  __shared__ float w2s[512 * 15];
  for (int i = threadIdx.x; i < 512 * 15; i += 256) w2s[i] = W2[i];
  __syncthreads();
  const int c = threadIdx.x & 63;
  const int d = blockIdx.x * 4 + (threadIdx.x >> 6);
  if (c >= 60 || d >= N_NODES) return;
  const int hop = c / 15, j = c % 15;
  const float4* hr4 = (const float4*)(Hh + (size_t)d * H_DIM);
  float acc = 0.f;
#pragma unroll 8
  for (int k4 = 0; k4 < 32; ++k4) {
    float4 h = hr4[k4];
    const float* wp = w2s + ((hop << 7) + k4 * 4) * 15 + j;
    acc = fmaf(h.x, wp[0],  acc);
    acc = fmaf(h.y, wp[15], acc);
    acc = fmaf(h.z, wp[30], acc);
    acc = fmaf(h.w, wp[45], acc);
  }
  Y2[(size_t)d * 64 + hop * 16 + j] = acc;
}

// ---- prop15g: 1 wave/row, 16 edges per float4 gather; stride-16 z rows ----
// lane = eidx*4 + fc. outStride 16 -> all lanes write float4; outStride 15
// (final, d_out) -> lanes 0-2 float4, lane 3 three scalars + bias.
__global__ __launch_bounds__(256) void k_prop15g(const int* __restrict__ rowStart,
    const int2* __restrict__ eSW,
    const float* __restrict__ in, int inStride, int inOff,
    const float* __restrict__ addv, int addStride, int addOff,
    const float* __restrict__ bias, float* __restrict__ out, int outStride) {
  const int lane = threadIdx.x & 63;
  const int wave = threadIdx.x >> 6;
  const int eidx = lane >> 2, fc = lane & 3;
  const int d = blockIdx.x * 4 + wave;
  const int s0 = rowStart[d], s1 = rowStart[d + 1];
  float4 acc = make_float4(0.f, 0.f, 0.f, 0.f);
  const int nc = (s1 - s0) >> 4;
  int j = s0;
  int2 ed = make_int2(0, 0);
  if (nc > 0) ed = eSW[j + eidx];
  for (int c = 0; c < nc; ++c) {
    float4 g = *(const float4*)(in + (size_t)ed.x * inStride + inOff + fc * 4);
    int2 edn = ed;
    if (c + 1 < nc) edn = eSW[j + 16 + eidx];
    float w = __int_as_float(ed.y);
    acc.x = fmaf(w, g.x, acc.x); acc.y = fmaf(w, g.y, acc.y);
    acc.z = fmaf(w, g.z, acc.z); acc.w = fmaf(w, g.w, acc.w);
    ed = edn; j += 16;
  }
#pragma unroll
  for (int m = 4; m <= 32; m <<= 1) {
    acc.x += __shfl_xor(acc.x, m); acc.y += __shfl_xor(acc.y, m);
    acc.z += __shfl_xor(acc.z, m); acc.w += __shfl_xor(acc.w, m);
  }
  if (lane >= 4) return;   // lane == fc
  float4 av = *(const float4*)(addv + (size_t)d * addStride + addOff + fc * 4);
  float r0 = av.x + acc.x, r1 = av.y + acc.y, r2 = av.z + acc.z, r3 = av.w + acc.w;
  if (outStride == 16) {
    *(float4*)(out + (size_t)d * 16 + fc * 4) = make_float4(r0, r1, r2, r3);
  } else {
    // final: add bias, stride 15, lane 3 writes 3 scalars (4B-aligned only)
    float* op = out + (size_t)d * 15 + fc * 4;
    if (fc < 3) {
      float4 bb = *(const float4*)(bias + fc * 4);
      *(float4*)op = make_float4(r0 + bb.x, r1 + bb.y, r2 + bb.z, r3 + bb.w);
    } else {
      op[0] = r0 + bias[12];
      op[1] = r1 + bias[13];
      op[2] = r2 + bias[14];
    }
  }
}

extern "C" void kernel_launch(void* const* d_in, const int* in_sizes, int n_in,
                              void* d_out, int out_size, void* d_ws, size_t ws_size,
                              hipStream_t stream) {
  const float* x     = (const float*)d_in[0];
  const int*   esrc  = (const int*)d_in[1];
  const int*   edst  = (const int*)d_in[2];
  const float* ew    = (const float*)d_in[3];
  const float* W1    = (const float*)d_in[4];
  const float* b1    = (const float*)d_in[5];
  const float* gamma = (const float*)d_in[6];
  const float* beta  = (const float*)d_in[7];
  const float* mmean = (const float*)d_in[8];
  const float* mvar  = (const float*)d_in[9];
  const float* W2    = (const float*)d_in[10];
  const float* b2    = (const float*)d_in[11];
  const int E = in_sizes[1];
  char* ws = (char*)d_ws;

  // workspace (127.9 MB total)
  unsigned short* xb  = (unsigned short*)(ws);              // 81,920,000  bf16 [20000][2048]
  float*          Y   = (float*)(ws + 81920000);            // 30,720,000  fp32 [20000][384]
  unsigned short* Yb3 = (unsigned short*)(ws + 112640000);  //  5,120,000  bf16 [20000][128]
  unsigned short* w1r = (unsigned short*)(ws + 117760000);  //  2,097,152
  int2*           eSW = (int2*)(ws + 119857152);            //  7,680,000 (padded CSR)
  int*       deg      = (int*)(ws + 127537152);             //     80,128
  int*       rowStart = (int*)(ws + 127617280);             //     80,128
  int*       cursor   = (int*)(ws + 127697408);             //     80,128
  int*       realEnd  = (int*)(ws + 127777536);             //     80,128
  // overlays on xb region (xb dead after k_gemm1)
  unsigned short* P   = (unsigned short*)(ws);              //  5,120,000  bf16
  unsigned short* Q   = (unsigned short*)(ws + 5120000);    //  5,120,000  bf16
  float*          Hb  = (float*)(ws + 10240000);            // 10,240,000
  float*          Y2  = (float*)(ws + 20480000);            //  5,120,000  fp32 [20000][64]
  float*          zP  = (float*)(ws + 25600000);            //  1,280,000  fp32 [20000][16]
  float*          zQ  = (float*)(ws + 26880000);            //  1,280,000  fp32 [20000][16]
  float*          zout = (float*)d_out;

  hipMemsetAsync(deg, 0, N_NODES * sizeof(int), stream);

  // padded CSR by dst (reused by all 6 propagations)
  k_hist<<<(E / 4 + 255) / 256 + 1, 256, 0, stream>>>(edst, deg, E);
  k_scan<<<1, 1024, 0, stream>>>(deg, rowStart, cursor, realEnd);
  k_scatter<<<(E + 255) / 256, 256, 0, stream>>>(esrc, edst, ew, cursor, eSW, E);
  k_pad<<<(N_NODES * 16) / 256, 256, 0, stream>>>(rowStart, realEnd, eSW);

  // GEMM1: [y0|y1|y2] fp32 + y3 bf16 (swizzled xb/w1r)
  k_cvt_x<<<(N_NODES * K_PAD / 8) / 256, 256, 0, stream>>>(x, xb);
  k_cvt_w1<<<128, 256, 0, stream>>>(W1, w1r);
  k_gemm1<<<1280, 256, 0, stream>>>(xb, w1r, Y, Yb3);

  // conv1 hops: h = relu(BN(y0 + A(y1 + A(y2 + A*y3)) + b1)); P,Q bf16
  k_prop128f<<<N_NODES / 4, 256, 0, stream>>>(rowStart, eSW, Yb3, Y, YS, 256,
                                              P, nullptr, b1, gamma, beta, mmean, mvar, 0);
  k_prop128f<<<N_NODES / 4, 256, 0, stream>>>(rowStart, eSW, P, Y, YS, 128,
                                              Q, nullptr, b1, gamma, beta, mmean, mvar, 0);
  k_prop128f<<<N_NODES / 4, 256, 0, stream>>>(rowStart, eSW, Q, Y, YS, 0,
                                              nullptr, Hb, b1, gamma, beta, mmean, mvar, 1);

  // GEMM2 + conv2 hops: z = u0 + A(u1 + A(u2 + A*u3)) + b2
  k_gemm2<<<N_NODES / 4, 256, 0, stream>>>(Hb, W2, Y2);
  k_prop15g<<<N_NODES / 4, 256, 0, stream>>>(rowStart, eSW, Y2, 64, 48, Y2, 64, 32, nullptr, zP, 16);
  k_prop15g<<<N_NODES / 4, 256, 0, stream>>>(rowStart, eSW, zP, 16, 0, Y2, 64, 16, nullptr, zQ, 16);
  k_prop15g<<<N_NODES / 4, 256, 0, stream>>>(rowStart, eSW, zQ, 16, 0, Y2, 64, 0, b2, zout, 15);
}

// Round 10
// 527.336 us; speedup vs baseline: 1.1072x; 1.1072x over previous
//
#include <hip/hip_runtime.h>
#include <hip/hip_bf16.h>
#include <cstdint>
#include <cstddef>

#define N_NODES 20000
#define F_IN    2000
#define H_DIM   128
#define L_DIM   15
#define K_PAD   2048      // padded K for xb/w1r layouts
#define YS      384       // Y fp32 stride (hops 0..2); hop3 lives in bf16 Yb3
#define BM      128
#define BN      64
#define BK      32        // one swizzle group; gemm1 stages 2 groups per barrier
#define I_TILES 157       // ceil(20000/128)

// bank-conflict swizzle for fragment reads (kept from R9; neutral but free)
#define FSW(r) (((r) + ((r) >> 2)) & 3)

typedef __attribute__((ext_vector_type(4))) float f32x4;
typedef __attribute__((ext_vector_type(8))) short s16x8;
typedef __attribute__((ext_vector_type(8))) unsigned short u16x8;

__device__ __forceinline__ unsigned short f2bf(float f) {
  unsigned int u = __float_as_uint(f);
  u += 0x7fff + ((u >> 16) & 1);   // RNE
  return (unsigned short)(u >> 16);
}

__device__ __forceinline__ unsigned int pkbf(float a, float b) {
  union { __hip_bfloat162 h; unsigned int u; } cv;
  cv.h = __float22bfloat162_rn(make_float2(a, b));
  return cv.u;
}

__device__ __forceinline__ float2 bf2f(unsigned int u) {
  float2 r;
  r.x = __uint_as_float(u << 16);
  r.y = __uint_as_float(u & 0xffff0000u);
  return r;
}

// ---- x (fp32 [20000][2000]) -> bf16 [20000][2048], slot-swizzled per 32-k group ----
__global__ __launch_bounds__(256) void k_cvt_x(const float* __restrict__ x,
                                               unsigned short* __restrict__ xb) {
  unsigned int t = blockIdx.x * 256u + threadIdx.x;
  unsigned int row = t >> 8;
  unsigned int colB = (t & 255u) * 8u;
  u16x8 o = {0, 0, 0, 0, 0, 0, 0, 0};
  if (colB < F_IN) {
    const float4 a = *(const float4*)(x + (size_t)row * F_IN + colB);
    const float4 b = *(const float4*)(x + (size_t)row * F_IN + colB + 4);
    o[0] = f2bf(a.x); o[1] = f2bf(a.y); o[2] = f2bf(a.z); o[3] = f2bf(a.w);
    o[4] = f2bf(b.x); o[5] = f2bf(b.y); o[6] = f2bf(b.z); o[7] = f2bf(b.w);
  }
  unsigned int s  = (colB >> 3) & 3;
  unsigned int sp = s ^ FSW(row & 15);
  *(u16x8*)(xb + (size_t)row * K_PAD + (colB & ~31u) + sp * 8) = o;
}

// ---- W1 [8000][128] -> bf16 B^T [512][2048], slot-swizzled per 32-k group ----
__global__ __launch_bounds__(256) void k_cvt_w1(const float* __restrict__ W1,
                                                unsigned short* __restrict__ bt) {
  __shared__ unsigned short tile[128 * 67];
  const int hop = blockIdx.x >> 5;
  const int k0  = (blockIdx.x & 31) * 64;
  const int t = threadIdx.x;
#pragma unroll
  for (int it = 0; it < 8; ++it) {
    int f4 = it * 256 + t;
    int r  = f4 >> 5;
    int c4 = f4 & 31;
    int k = k0 + r;
    float4 v = make_float4(0.f, 0.f, 0.f, 0.f);
    if (k < F_IN) v = *(const float4*)(W1 + (size_t)(hop * F_IN + k) * H_DIM + c4 * 4);
    tile[(c4 * 4 + 0) * 67 + r] = f2bf(v.x);
    tile[(c4 * 4 + 1) * 67 + r] = f2bf(v.y);
    tile[(c4 * 4 + 2) * 67 + r] = f2bf(v.z);
    tile[(c4 * 4 + 3) * 67 + r] = f2bf(v.w);
  }
  __syncthreads();
  const int c = t >> 1, kh = (t & 1) * 32;     // kh: one full 32-k group
  const int fN = FSW(c & 15);
  unsigned short* dst = bt + (size_t)(hop * 128 + c) * K_PAD + k0 + kh;
  const unsigned short* srcp = tile + c * 67 + kh;
#pragma unroll
  for (int q = 0; q < 4; ++q) {
    u16x8 o;
#pragma unroll
    for (int e = 0; e < 8; ++e) o[e] = srcp[q * 8 + e];
    *(u16x8*)(dst + (q ^ fN) * 8) = o;
  }
}

// ---- bf16 MFMA GEMM, 128x64 tiles, 64-k per barrier (2 swizzle groups) ----
// grid = 1280 1D; xcd=b&7, i_tile=(b&7)+8*(b>>6), j_tile=(b>>3)&7
__global__ __launch_bounds__(256) void k_gemm1(const unsigned short* __restrict__ A,
                                               const unsigned short* __restrict__ B,
                                               float* __restrict__ Y,
                                               unsigned short* __restrict__ Yb3) {
  __shared__ unsigned short As[2][BM * BK];   // 2 x 8 KB
  __shared__ unsigned short Bs[2][BN * BK];   // 2 x 4 KB
  const int b = blockIdx.x;
  const int i_tile = (b & 7) + 8 * (b >> 6);
  const int j_tile = (b >> 3) & 7;
  if (i_tile >= I_TILES) return;
  const int rowA0 = i_tile * BM;
  const int colB0 = j_tile * BN;
  const int tid  = threadIdx.x;
  const int lane = tid & 63;
  const int wave = tid >> 6;
  const int wm = (wave >> 1) * 64;
  const int wn = (wave & 1) * 32;
  const int quad = lane >> 4;
  const int l15  = lane & 15;
  const int qs   = (quad ^ FSW(l15)) * 8;   // swizzled slot offset (shorts)
  f32x4 acc[4][2] = {};

  for (int kt = 0; kt < K_PAD; kt += 64) {
#pragma unroll
    for (int h = 0; h < 2; ++h) {
#pragma unroll
      for (int r = 0; r < 2; ++r) {
        int c = r * 256 + tid;
        int row = c >> 2;
        int kc = (c & 3) * 8;
        const unsigned short* ga = A + (size_t)(rowA0 + row) * K_PAD + kt + h * 32 + kc;
        __builtin_amdgcn_global_load_lds((const __attribute__((address_space(1))) void*)ga,
                                         (__attribute__((address_space(3))) void*)(As[h] + c * 8),
                                         16, 0, 0);
      }
      {
        int c = tid;
        int row = c >> 2;
        int kc = (c & 3) * 8;
        const unsigned short* gb = B + (size_t)(colB0 + row) * K_PAD + kt + h * 32 + kc;
        __builtin_amdgcn_global_load_lds((const __attribute__((address_space(1))) void*)gb,
                                         (__attribute__((address_space(3))) void*)(Bs[h] + c * 8),
                                         16, 0, 0);
      }
    }
    __syncthreads();
#pragma unroll
    for (int h = 0; h < 2; ++h) {
      s16x8 af[4], bfr[2];
#pragma unroll
      for (int i = 0; i < 4; ++i)
        af[i] = *(const s16x8*)(As[h] + (wm + i * 16 + l15) * BK + qs);
#pragma unroll
      for (int j = 0; j < 2; ++j)
        bfr[j] = *(const s16x8*)(Bs[h] + (wn + j * 16 + l15) * BK + qs);
#pragma unroll
      for (int i = 0; i < 4; ++i)
#pragma unroll
        for (int j = 0; j < 2; ++j)
          acc[i][j] = __builtin_amdgcn_mfma_f32_16x16x32_bf16(af[i], bfr[j], acc[i][j], 0, 0, 0);
    }
    __syncthreads();
  }

#pragma unroll
  for (int i = 0; i < 4; ++i) {
    int row0 = rowA0 + wm + i * 16 + quad * 4;
#pragma unroll
    for (int j = 0; j < 2; ++j) {
      int gcol = colB0 + wn + j * 16 + l15;
#pragma unroll
      for (int r = 0; r < 4; ++r) {
        int row = row0 + r;
        if (row < N_NODES) {
          if (j_tile < 6)
            Y[(size_t)row * YS + gcol] = acc[i][j][r];
          else
            Yb3[(size_t)row * H_DIM + (gcol - 384)] = f2bf(acc[i][j][r]);
        }
      }
    }
  }
}

// ---- CSR build (padded to multiple of 8), parallel scan ----
__global__ __launch_bounds__(256) void k_hist(const int* __restrict__ dst,
                                              int* __restrict__ deg, int E) {
  int i = blockIdx.x * 256 + threadIdx.x;
  int e = i * 4;
  if (e + 4 <= E) {
    int4 d4 = *(const int4*)(dst + e);
    atomicAdd(&deg[d4.x], 1); atomicAdd(&deg[d4.y], 1);
    atomicAdd(&deg[d4.z], 1); atomicAdd(&deg[d4.w], 1);
  } else {
    for (; e < E; ++e) atomicAdd(&deg[dst[e]], 1);
  }
}

// per-block sums of padded degrees (79 blocks x 256 nodes)
__global__ __launch_bounds__(256) void k_bsum(const int* __restrict__ deg,
                                              int* __restrict__ bsum) {
  __shared__ int red[256];
  int g = blockIdx.x * 256 + threadIdx.x;
  int pd = 0;
  if (g < N_NODES) pd = (deg[g] + 7) & ~7;
  red[threadIdx.x] = pd;
  __syncthreads();
  for (int o = 128; o > 0; o >>= 1) {
    if (threadIdx.x < (unsigned)o) red[threadIdx.x] += red[threadIdx.x + o];
    __syncthreads();
  }
  if (threadIdx.x == 0) bsum[blockIdx.x] = red[0];
}

// exclusive scan of 79 block sums (1 block, 128 threads)
__global__ __launch_bounds__(128) void k_scan80(const int* __restrict__ bsum,
                                                int* __restrict__ boff) {
  __shared__ int s[128];
  int t = threadIdx.x;
  int v = (t < 79) ? bsum[t] : 0;
  s[t] = v;
  __syncthreads();
  for (int o = 1; o < 128; o <<= 1) {
    int cur = s[t];
    int u = (t >= o) ? s[t - o] : 0;
    __syncthreads();
    s[t] = cur + u;
    __syncthreads();
  }
  if (t < 79) boff[t] = s[t] - v;
}

// per-node offsets via in-block scan + block offset
__global__ __launch_bounds__(256) void k_fill(const int* __restrict__ deg,
                                              const int* __restrict__ boff,
                                              int* __restrict__ rowStart,
                                              int* __restrict__ cursor,
                                              int* __restrict__ realEnd) {
  __shared__ int s[256];
  int t = threadIdx.x;
  int g = blockIdx.x * 256 + t;
  int dv = (g < N_NODES) ? deg[g] : 0;
  int pd = (dv + 7) & ~7;
  s[t] = pd;
  __syncthreads();
  for (int o = 1; o < 256; o <<= 1) {
    int cur = s[t];
    int u = (t >= o) ? s[t - o] : 0;
    __syncthreads();
    s[t] = cur + u;
    __syncthreads();
  }
  int rs = boff[blockIdx.x] + s[t] - pd;
  if (g < N_NODES) {
    rowStart[g] = rs; cursor[g] = rs; realEnd[g] = rs + dv;
    if (g == N_NODES - 1) rowStart[N_NODES] = rs + pd;
  }
}

__global__ __launch_bounds__(256) void k_scatter(const int* __restrict__ src,
                                                 const int* __restrict__ dst,
                                                 const float* __restrict__ w,
                                                 int* cursor,
                                                 int2* __restrict__ eSW, int E) {
  int e = blockIdx.x * 256 + threadIdx.x;
  if (e >= E) return;
  int p = atomicAdd(&cursor[dst[e]], 1);
  eSW[p] = make_int2(src[e], __float_as_int(w[e]));
}

// fill pad slots [realEnd, nextRowStart) with {src=0, w=0}; <=7 pads/row
__global__ __launch_bounds__(256) void k_pad(const int* __restrict__ rowStart,
                                             const int* __restrict__ realEnd,
                                             int2* __restrict__ eSW) {
  int t = blockIdx.x * 256 + threadIdx.x;
  int d = t >> 3, i = t & 7;
  if (d >= N_NODES) return;
  int s = realEnd[d] + i;
  if (s < rowStart[d + 1]) eSW[s] = make_int2(0, 0);
}

// ---- prop128f: 1 wave/row; 16-edge main chunks (4 edges/instr) + 8-edge tail ----
__global__ __launch_bounds__(256) void k_prop128f(const int* __restrict__ rowStart,
    const int2* __restrict__ eSW,
    const unsigned short* __restrict__ gsrc,   // bf16 [N_NODES][128]
    const float* __restrict__ addv, int addStride, int addOff,
    unsigned short* __restrict__ outb, float* __restrict__ outf,
    const float* __restrict__ b1, const float* __restrict__ gamma,
    const float* __restrict__ beta, const float* __restrict__ mean,
    const float* __restrict__ var, int doBN) {
  const int lane = threadIdx.x & 63;
  const int wave = threadIdx.x >> 6;
  const int eidx = lane >> 4;        // 0..3
  const int s16  = lane & 15;        // feats [s16*8, s16*8+8)
  const int d = blockIdx.x * 4 + wave;
  const int s0 = rowStart[d], s1 = rowStart[d + 1];
  f32x4 a0 = {0.f, 0.f, 0.f, 0.f};
  f32x4 a1 = {0.f, 0.f, 0.f, 0.f};

  const int n = s1 - s0;             // multiple of 8
  const int nc = n >> 4;             // 16-edge chunks
  int j = s0;
  int2 ed0[4], ed1[4];
  if (nc > 0) {
#pragma unroll
    for (int i = 0; i < 4; ++i) ed0[i] = eSW[j + 4 * i + eidx];
  }
  for (int c = 0; c < nc; ++c) {
    uint4 g[4];
#pragma unroll
    for (int i = 0; i < 4; ++i)
      g[i] = *(const uint4*)(gsrc + (size_t)ed0[i].x * H_DIM + s16 * 8);
    if (c + 1 < nc) {
#pragma unroll
      for (int i = 0; i < 4; ++i) ed1[i] = eSW[j + 16 + 4 * i + eidx];
    }
#pragma unroll
    for (int i = 0; i < 4; ++i) {
      float w = __int_as_float(ed0[i].y);
      float2 p0 = bf2f(g[i].x), p1 = bf2f(g[i].y);
      float2 p2 = bf2f(g[i].z), p3 = bf2f(g[i].w);
      a0.x = fmaf(w, p0.x, a0.x); a0.y = fmaf(w, p0.y, a0.y);
      a0.z = fmaf(w, p1.x, a0.z); a0.w = fmaf(w, p1.y, a0.w);
      a1.x = fmaf(w, p2.x, a1.x); a1.y = fmaf(w, p2.y, a1.y);
      a1.z = fmaf(w, p3.x, a1.z); a1.w = fmaf(w, p3.y, a1.w);
    }
#pragma unroll
    for (int i = 0; i < 4; ++i) ed0[i] = ed1[i];
    j += 16;
  }
  if (n & 8) {                       // one 8-edge tail (2 gathers)
    int2 ta[2];
    ta[0] = eSW[j + eidx];
    ta[1] = eSW[j + 4 + eidx];
#pragma unroll
    for (int i = 0; i < 2; ++i) {
      uint4 g = *(const uint4*)(gsrc + (size_t)ta[i].x * H_DIM + s16 * 8);
      float w = __int_as_float(ta[i].y);
      float2 p0 = bf2f(g.x), p1 = bf2f(g.y);
      float2 p2 = bf2f(g.z), p3 = bf2f(g.w);
      a0.x = fmaf(w, p0.x, a0.x); a0.y = fmaf(w, p0.y, a0.y);
      a0.z = fmaf(w, p1.x, a0.z); a0.w = fmaf(w, p1.y, a0.w);
      a1.x = fmaf(w, p2.x, a1.x); a1.y = fmaf(w, p2.y, a1.y);
      a1.z = fmaf(w, p3.x, a1.z); a1.w = fmaf(w, p3.y, a1.w);
    }
  }
  a0.x += __shfl_xor(a0.x, 16); a0.y += __shfl_xor(a0.y, 16);
  a0.z += __shfl_xor(a0.z, 16); a0.w += __shfl_xor(a0.w, 16);
  a1.x += __shfl_xor(a1.x, 16); a1.y += __shfl_xor(a1.y, 16);
  a1.z += __shfl_xor(a1.z, 16); a1.w += __shfl_xor(a1.w, 16);
  a0.x += __shfl_xor(a0.x, 32); a0.y += __shfl_xor(a0.y, 32);
  a0.z += __shfl_xor(a0.z, 32); a0.w += __shfl_xor(a0.w, 32);
  a1.x += __shfl_xor(a1.x, 32); a1.y += __shfl_xor(a1.y, 32);
  a1.z += __shfl_xor(a1.z, 32); a1.w += __shfl_xor(a1.w, 32);
  if (lane >= 16) return;
  const int c8 = s16 * 8;
  const float* ap = addv + (size_t)d * addStride + addOff + c8;
  float4 av0 = *(const float4*)ap;
  float4 av1 = *(const float4*)(ap + 4);
  float r0 = av0.x + a0.x, r1 = av0.y + a0.y, r2 = av0.z + a0.z, r3 = av0.w + a0.w;
  float r4 = av1.x + a1.x, r5 = av1.y + a1.y, r6 = av1.z + a1.z, r7 = av1.w + a1.w;
  if (doBN) {
    float4 bb0 = *(const float4*)(b1 + c8),    bb1 = *(const float4*)(b1 + c8 + 4);
    float4 gg0 = *(const float4*)(gamma + c8), gg1 = *(const float4*)(gamma + c8 + 4);
    float4 be0 = *(const float4*)(beta + c8),  be1 = *(const float4*)(beta + c8 + 4);
    float4 mm0 = *(const float4*)(mean + c8),  mm1 = *(const float4*)(mean + c8 + 4);
    float4 vv0 = *(const float4*)(var + c8),   vv1 = *(const float4*)(var + c8 + 4);
    r0 = (r0 + bb0.x - mm0.x) * rsqrtf(vv0.x + 1e-3f) * gg0.x + be0.x;
    r1 = (r1 + bb0.y - mm0.y) * rsqrtf(vv0.y + 1e-3f) * gg0.y + be0.y;
    r2 = (r2 + bb0.z - mm0.z) * rsqrtf(vv0.z + 1e-3f) * gg0.z + be0.z;
    r3 = (r3 + bb0.w - mm0.w) * rsqrtf(vv0.w + 1e-3f) * gg0.w + be0.w;
    r4 = (r4 + bb1.x - mm1.x) * rsqrtf(vv1.x + 1e-3f) * gg1.x + be1.x;
    r5 = (r5 + bb1.y - mm1.y) * rsqrtf(vv1.y + 1e-3f) * gg1.y + be1.y;
    r6 = (r6 + bb1.z - mm1.z) * rsqrtf(vv1.z + 1e-3f) * gg1.z + be1.z;
    r7 = (r7 + bb1.w - mm1.w) * rsqrtf(vv1.w + 1e-3f) * gg1.w + be1.w;
    r0 = r0 > 0.f ? r0 : 0.f; r1 = r1 > 0.f ? r1 : 0.f;
    r2 = r2 > 0.f ? r2 : 0.f; r3 = r3 > 0.f ? r3 : 0.f;
    r4 = r4 > 0.f ? r4 : 0.f; r5 = r5 > 0.f ? r5 : 0.f;
    r6 = r6 > 0.f ? r6 : 0.f; r7 = r7 > 0.f ? r7 : 0.f;
    float* op = outf + (size_t)d * H_DIM + c8;
    *(float4*)op = make_float4(r0, r1, r2, r3);
    *(float4*)(op + 4) = make_float4(r4, r5, r6, r7);
  } else {
    *(uint4*)(outb + (size_t)d * H_DIM + c8) =
        make_uint4(pkbf(r0, r1), pkbf(r2, r3), pkbf(r4, r5), pkbf(r6, r7));
  }
}

// ---- Y2[20000][64] = H @ W2 (4 hop-blocks of [128][15], stride 16/hop) ----
__global__ __launch_bounds__(256) void k_gemm2(const float* __restrict__ Hh,
                                               const float* __restrict__ W2,
                                               float* __restrict__ Y2) {
  __shared__ float w2s[512 * 15];
  for (int i = threadIdx.x; i < 512 * 15; i += 256) w2s[i] = W2[i];
  __syncthreads();
  const int c = threadIdx.x & 63;
  const int d = blockIdx.x * 4 + (threadIdx.x >> 6);
  if (c >= 60 || d >= N_NODES) return;
  const int hop = c / 15, j = c % 15;
  const float4* hr4 = (const float4*)(Hh + (size_t)d * H_DIM);
  float acc = 0.f;
#pragma unroll 8
  for (int k4 = 0; k4 < 32; ++k4) {
    float4 h = hr4[k4];
    const float* wp = w2s + ((hop << 7) + k4 * 4) * 15 + j;
    acc = fmaf(h.x, wp[0],  acc);
    acc = fmaf(h.y, wp[15], acc);
    acc = fmaf(h.z, wp[30], acc);
    acc = fmaf(h.w, wp[45], acc);
  }
  Y2[(size_t)d * 64 + hop * 16 + j] = acc;
}

// ---- prop15g: 1 wave/row; 16-edge chunks (1 gather instr) + 8-edge tail ----
__global__ __launch_bounds__(256) void k_prop15g(const int* __restrict__ rowStart,
    const int2* __restrict__ eSW,
    const float* __restrict__ in, int inStride, int inOff,
    const float* __restrict__ addv, int addStride, int addOff,
    const float* __restrict__ bias, float* __restrict__ out, int outStride) {
  const int lane = threadIdx.x & 63;
  const int wave = threadIdx.x >> 6;
  const int eidx = lane >> 2, fc = lane & 3;
  const int d = blockIdx.x * 4 + wave;
  const int s0 = rowStart[d], s1 = rowStart[d + 1];
  float4 acc = make_float4(0.f, 0.f, 0.f, 0.f);
  const int n = s1 - s0;
  const int nc = n >> 4;
  int j = s0;
  int2 ed = make_int2(0, 0);
  if (nc > 0) ed = eSW[j + eidx];
  for (int c = 0; c < nc; ++c) {
    float4 g = *(const float4*)(in + (size_t)ed.x * inStride + inOff + fc * 4);
    int2 edn = ed;
    if (c + 1 < nc) edn = eSW[j + 16 + eidx];
    float w = __int_as_float(ed.y);
    acc.x = fmaf(w, g.x, acc.x); acc.y = fmaf(w, g.y, acc.y);
    acc.z = fmaf(w, g.z, acc.z); acc.w = fmaf(w, g.w, acc.w);
    ed = edn; j += 16;
  }
  if ((n & 8) && eidx < 8) {         // 8-edge tail on half the lanes
    int2 e = eSW[j + eidx];
    float4 g = *(const float4*)(in + (size_t)e.x * inStride + inOff + fc * 4);
    float w = __int_as_float(e.y);
    acc.x = fmaf(w, g.x, acc.x); acc.y = fmaf(w, g.y, acc.y);
    acc.z = fmaf(w, g.z, acc.z); acc.w = fmaf(w, g.w, acc.w);
  }
#pragma unroll
  for (int m = 4; m <= 32; m <<= 1) {
    acc.x += __shfl_xor(acc.x, m); acc.y += __shfl_xor(acc.y, m);
    acc.z += __shfl_xor(acc.z, m); acc.w += __shfl_xor(acc.w, m);
  }
  if (lane >= 4) return;   // lane == fc
  float4 av = *(const float4*)(addv + (size_t)d * addStride + addOff + fc * 4);
  float r0 = av.x + acc.x, r1 = av.y + acc.y, r2 = av.z + acc.z, r3 = av.w + acc.w;
  if (outStride == 16) {
    *(float4*)(out + (size_t)d * 16 + fc * 4) = make_float4(r0, r1, r2, r3);
  } else {
    float* op = out + (size_t)d * 15 + fc * 4;
    if (fc < 3) {
      float4 bb = *(const float4*)(bias + fc * 4);
      *(float4*)op = make_float4(r0 + bb.x, r1 + bb.y, r2 + bb.z, r3 + bb.w);
    } else {
      op[0] = r0 + bias[12];
      op[1] = r1 + bias[13];
      op[2] = r2 + bias[14];
    }
  }
}

extern "C" void kernel_launch(void* const* d_in, const int* in_sizes, int n_in,
                              void* d_out, int out_size, void* d_ws, size_t ws_size,
                              hipStream_t stream) {
  const float* x     = (const float*)d_in[0];
  const int*   esrc  = (const int*)d_in[1];
  const int*   edst  = (const int*)d_in[2];
  const float* ew    = (const float*)d_in[3];
  const float* W1    = (const float*)d_in[4];
  const float* b1    = (const float*)d_in[5];
  const float* gamma = (const float*)d_in[6];
  const float* beta  = (const float*)d_in[7];
  const float* mmean = (const float*)d_in[8];
  const float* mvar  = (const float*)d_in[9];
  const float* W2    = (const float*)d_in[10];
  const float* b2    = (const float*)d_in[11];
  const int E = in_sizes[1];
  char* ws = (char*)d_ws;

  // workspace (~128 MB)
  unsigned short* xb  = (unsigned short*)(ws);              // 81,920,000  bf16 [20000][2048]
  float*          Y   = (float*)(ws + 81920000);            // 30,720,000  fp32 [20000][384]
  unsigned short* Yb3 = (unsigned short*)(ws + 112640000);  //  5,120,000  bf16 [20000][128]
  unsigned short* w1r = (unsigned short*)(ws + 117760000);  //  2,097,152
  int2*           eSW = (int2*)(ws + 119857152);            //  7,680,000 (padded CSR)
  int*       deg      = (int*)(ws + 127537152);             //     80,128
  int*       rowStart = (int*)(ws + 127617280);             //     80,128
  int*       cursor   = (int*)(ws + 127697408);             //     80,128
  int*       realEnd  = (int*)(ws + 127777536);             //     80,128
  int*       bsum     = (int*)(ws + 127857664);             //        512
  int*       boff     = (int*)(ws + 127858176);             //        512
  // overlays on xb region (xb dead after k_gemm1)
  unsigned short* P   = (unsigned short*)(ws);              //  5,120,000  bf16
  unsigned short* Q   = (unsigned short*)(ws + 5120000);    //  5,120,000  bf16
  float*          Hb  = (float*)(ws + 10240000);            // 10,240,000
  float*          Y2  = (float*)(ws + 20480000);            //  5,120,000  fp32 [20000][64]
  float*          zP  = (float*)(ws + 25600000);            //  1,280,000  fp32 [20000][16]
  float*          zQ  = (float*)(ws + 26880000);            //  1,280,000  fp32 [20000][16]
  float*          zout = (float*)d_out;

  hipMemsetAsync(deg, 0, N_NODES * sizeof(int), stream);

  // padded CSR by dst (parallel scan), reused by all 6 propagations
  k_hist<<<(E / 4 + 255) / 256 + 1, 256, 0, stream>>>(edst, deg, E);
  k_bsum<<<79, 256, 0, stream>>>(deg, bsum);
  k_scan80<<<1, 128, 0, stream>>>(bsum, boff);
  k_fill<<<79, 256, 0, stream>>>(deg, boff, rowStart, cursor, realEnd);
  k_scatter<<<(E + 255) / 256, 256, 0, stream>>>(esrc, edst, ew, cursor, eSW, E);
  k_pad<<<(N_NODES * 8) / 256, 256, 0, stream>>>(rowStart, realEnd, eSW);

  // GEMM1: [y0|y1|y2] fp32 + y3 bf16 (swizzled xb/w1r, 64-k per barrier)
  k_cvt_x<<<(N_NODES * K_PAD / 8) / 256, 256, 0, stream>>>(x, xb);
  k_cvt_w1<<<128, 256, 0, stream>>>(W1, w1r);
  k_gemm1<<<1280, 256, 0, stream>>>(xb, w1r, Y, Yb3);

  // conv1 hops: h = relu(BN(y0 + A(y1 + A(y2 + A*y3)) + b1)); P,Q bf16
  k_prop128f<<<N_NODES / 4, 256, 0, stream>>>(rowStart, eSW, Yb3, Y, YS, 256,
                                              P, nullptr, b1, gamma, beta, mmean, mvar, 0);
  k_prop128f<<<N_NODES / 4, 256, 0, stream>>>(rowStart, eSW, P, Y, YS, 128,
                                              Q, nullptr, b1, gamma, beta, mmean, mvar, 0);
  k_prop128f<<<N_NODES / 4, 256, 0, stream>>>(rowStart, eSW, Q, Y, YS, 0,
                                              nullptr, Hb, b1, gamma, beta, mmean, mvar, 1);

  // GEMM2 + conv2 hops: z = u0 + A(u1 + A(u2 + A*u3)) + b2
  k_gemm2<<<N_NODES / 4, 256, 0, stream>>>(Hb, W2, Y2);
  k_prop15g<<<N_NODES / 4, 256, 0, stream>>>(rowStart, eSW, Y2, 64, 48, Y2, 64, 32, nullptr, zP, 16);
  k_prop15g<<<N_NODES / 4, 256, 0, stream>>>(rowStart, eSW, zP, 16, 0, Y2, 64, 16, nullptr, zQ, 16);
  k_prop15g<<<N_NODES / 4, 256, 0, stream>>>(rowStart, eSW, zQ, 16, 0, Y2, 64, 0, b2, zout, 15);
}